// Round 5
// baseline (983.091 us; speedup 1.0000x reference)
//
#include <hip/hip_runtime.h>
#include <hip/hip_bf16.h>
#include <math.h>

typedef __bf16 bf16_t;
typedef __bf16 bf16x8 __attribute__((ext_vector_type(8)));
typedef float f32x4 __attribute__((ext_vector_type(4)));
typedef unsigned short u16;

#define NB   40
#define NT   20
#define FEA  200
#define HD   1024
#define NOUT 1095
#define NL   12
#define M_ROWS 800      // NB*NT
#define UPITCH 196      // fp32 pitch for U in LDS (192 + 4 pad)
#define NBLK 160        // fused-kernel grid: 16 col-blocks x 10 batch-groups

// ---------------------------------------------------------------------------
// Transpose+convert: src fp32 [srcK][srcN] -> dst bf16 [Np][Kp], zero-padded.
// 64x64 tile via LDS (pitch 66 u16, conflict-free). blockIdx.z = layer.
// ---------------------------------------------------------------------------
__global__ __launch_bounds__(256)
void transpose_convert(const float* __restrict__ src, bf16_t* __restrict__ dst,
                       int srcK, int srcN, int Kp, int Np)
{
    __shared__ u16 tile[64 * 66];
    const int t = threadIdx.x;
    src += (size_t)blockIdx.z * srcK * srcN;
    dst += (size_t)blockIdx.z * Np * Kp;
    const int n0 = blockIdx.x << 6, k0 = blockIdx.y << 6;
    {
        const int nl = t & 63, kb = (t >> 6) << 4;
        const int gn = n0 + nl;
        #pragma unroll
        for (int j = 0; j < 16; j++) {
            const int gk = k0 + kb + j;
            float v = (gk < srcK && gn < srcN) ? src[(size_t)gk * srcN + gn] : 0.f;
            bf16_t b = (bf16_t)v;
            tile[nl * 66 + kb + j] = *(const u16*)&b;
        }
    }
    __syncthreads();
    {
        const int nl = t >> 2, kg = (t & 3) << 4;
        const unsigned* tp = (const unsigned*)tile;
        const int dw = nl * 33 + (kg >> 1);
        uint4 v0, v1;
        v0.x = tp[dw+0]; v0.y = tp[dw+1]; v0.z = tp[dw+2]; v0.w = tp[dw+3];
        v1.x = tp[dw+4]; v1.y = tp[dw+5]; v1.z = tp[dw+6]; v1.w = tp[dw+7];
        bf16_t* dp = dst + (size_t)(n0 + nl) * Kp + k0 + kg;
        *(uint4*)dp = v0;
        *(uint4*)(dp + 8) = v1;
    }
}

// x [800][200] fp32 -> xb [800][256] bf16 zero-padded.
__global__ __launch_bounds__(256)
void convert_pad_x(const float* __restrict__ src, bf16_t* __restrict__ dst)
{
    const int m = blockIdx.x, k = threadIdx.x;
    dst[m * 256 + k] = (bf16_t)((k < FEA) ? src[(size_t)m * FEA + k] : 0.f);
}

// ---------------------------------------------------------------------------
// Grid barrier: single-use counter, device-scope release/acquire.
// Requires all blocks co-resident (NBLK=160 <= 256 CUs, 1 block/CU fits).
// ---------------------------------------------------------------------------
__device__ __forceinline__ void grid_barrier(unsigned* cnt, unsigned target)
{
    __syncthreads();
    if (threadIdx.x == 0) {
        __threadfence();
        __hip_atomic_fetch_add(cnt, 1u, __ATOMIC_RELEASE, __HIP_MEMORY_SCOPE_AGENT);
        while (__hip_atomic_load(cnt, __ATOMIC_ACQUIRE, __HIP_MEMORY_SCOPE_AGENT) < target)
            __builtin_amdgcn_s_sleep(1);
    }
    __syncthreads();
}

// ---------------------------------------------------------------------------
// Direct-fragment GEMM tile (64 rows x 64 cols): C = A[M,Ks]bf16 @ Bt[n][k]
// (+bias fp32)(+relu). Wave w -> row-subtile, 4 col-tiles. No LDS/barriers.
// Layouts (verified): A[m=l16][k=quad*8+j], B[n=l16][k=quad*8+j],
// D col=l16, row=quad*4+reg.
// ---------------------------------------------------------------------------
template<bool OUT_F32, bool RELU>
__device__ __forceinline__
void gemm_tile(const bf16_t* __restrict__ A, const bf16_t* __restrict__ Bt,
               const float* __restrict__ bias, void* __restrict__ C,
               int M, int Nstore, int Ks, int n0, int mb)
{
    const int tid = threadIdx.x;
    const int w = tid >> 6, lane = tid & 63, quad = lane >> 4, l16 = lane & 15;
    const int r0 = (mb * 4 + w) << 4;

    int arow = r0 + l16; if (arow > M - 1) arow = M - 1;
    const bf16_t* ap = A + (size_t)arow * Ks + quad * 8;
    const bf16_t* bp[4];
    #pragma unroll
    for (int ct = 0; ct < 4; ct++)
        bp[ct] = Bt + (size_t)(n0 + ct * 16 + l16) * Ks + quad * 8;

    f32x4 acc[4];
    #pragma unroll
    for (int i = 0; i < 4; i++) acc[i] = (f32x4){0.f, 0.f, 0.f, 0.f};

    #pragma unroll 2
    for (int k0 = 0; k0 < Ks; k0 += 32) {
        bf16x8 a = *(const bf16x8*)(ap + k0);
        #pragma unroll
        for (int ct = 0; ct < 4; ct++) {
            bf16x8 b = *(const bf16x8*)(bp[ct] + k0);
            acc[ct] = __builtin_amdgcn_mfma_f32_16x16x32_bf16(a, b, acc[ct], 0, 0, 0);
        }
    }

    #pragma unroll
    for (int ct = 0; ct < 4; ct++) {
        const int col = n0 + ct * 16 + l16;
        if (col >= Nstore) continue;
        const float bv = bias ? bias[col] : 0.f;
        #pragma unroll
        for (int i = 0; i < 4; i++) {
            const int m = r0 + quad * 4 + i;
            if (m < M) {
                float v = acc[ct][i] + bv;
                if (RELU) v = v > 0.f ? v : 0.f;
                if (OUT_F32) ((float*)C)[(size_t)m * Nstore + col] = v;
                else         ((bf16_t*)C)[(size_t)m * Nstore + col] = (bf16_t)v;
            }
        }
    }
}

// ---------------------------------------------------------------------------
// One SRU layer's work for this block: (n0 = 64 h-cols, bi = 4 batches).
// GEMM M=80,N=192,K=1024 direct-fragment; U -> LDS fp32; 20-step scan.
// ---------------------------------------------------------------------------
__device__ __forceinline__
void sru_tile(const bf16_t* __restrict__ hin, bf16_t* __restrict__ hout,
              const bf16_t* __restrict__ Wt, const float* __restrict__ c0,
              const float* __restrict__ bvec, float* __restrict__ cout,
              int n0, int bi, float* __restrict__ Ul)
{
    const int tid = threadIdx.x;
    const int w = tid >> 6, lane = tid & 63, quad = lane >> 4, l16 = lane & 15;

    f32x4 acc[5][3];
    #pragma unroll
    for (int rt = 0; rt < 5; rt++)
        #pragma unroll
        for (int ct = 0; ct < 3; ct++) acc[rt][ct] = (f32x4){0.f, 0.f, 0.f, 0.f};

    const bf16_t* bp[3];
    #pragma unroll
    for (int ct = 0; ct < 3; ct++) {
        const int ctt = w * 3 + ct;   // U col-tile; gate=ctt>>2, 16-col chunk=ctt&3
        bp[ct] = Wt + (size_t)((ctt >> 2) * HD + n0 + ((ctt & 3) << 4) + l16) * HD + quad * 8;
    }
    const bf16_t* ap[5];
    #pragma unroll
    for (int rt = 0; rt < 5; rt++)
        ap[rt] = hin + (size_t)(bi * 80 + rt * 16 + l16) * HD + quad * 8;

    #pragma unroll 2
    for (int k0 = 0; k0 < HD; k0 += 32) {
        bf16x8 a[5], b[3];
        #pragma unroll
        for (int rt = 0; rt < 5; rt++) a[rt] = *(const bf16x8*)(ap[rt] + k0);
        #pragma unroll
        for (int ct = 0; ct < 3; ct++) b[ct] = *(const bf16x8*)(bp[ct] + k0);
        #pragma unroll
        for (int rt = 0; rt < 5; rt++)
            #pragma unroll
            for (int ct = 0; ct < 3; ct++)
                acc[rt][ct] = __builtin_amdgcn_mfma_f32_16x16x32_bf16(a[rt], b[ct], acc[rt][ct], 0, 0, 0);
    }

    #pragma unroll
    for (int rt = 0; rt < 5; rt++)
        #pragma unroll
        for (int ct = 0; ct < 3; ct++) {
            const int col = (w * 3 + ct) * 16 + l16;
            #pragma unroll
            for (int i = 0; i < 4; i++)
                Ul[(rt * 16 + quad * 4 + i) * UPITCH + col] = acc[rt][ct][i];
        }
    __syncthreads();

    const int bl = tid >> 6, nn = tid & 63, bg = bi * 4 + bl;
    float c = c0[(size_t)bg * HD + n0 + nn];
    const float bfb = bvec[n0 + nn], brb = bvec[HD + n0 + nn];

    for (int t = 0; t < NT; t++) {
        const float* u = &Ul[(bl * NT + t) * UPITCH];
        const float xt = u[nn];
        const float uf = u[64 + nn];
        const float ur = u[128 + nn];
        const float f = 1.f / (1.f + __expf(-(uf + bfb)));
        const float r = 1.f / (1.f + __expf(-(ur + brb)));
        c = f * c + (1.f - f) * xt;
        const size_t gi = (size_t)(bg * NT + t) * HD + n0 + nn;
        const float hp = (float)hin[gi];
        hout[gi] = (bf16_t)(r * tanhf(c) + (1.f - r) * hp);
    }
    cout[(size_t)bg * HD + n0 + nn] = c;
}

// ---------------------------------------------------------------------------
// Fused network: dense1 + 12 SRU layers + dense3(relu) + dense4, with grid
// barriers between phases. Grid = exactly NBLK=160 blocks (co-resident).
// ---------------------------------------------------------------------------
__global__ __launch_bounds__(256, 1)
void fused_net(const bf16_t* __restrict__ xb, const bf16_t* __restrict__ w1t,
               const float* __restrict__ b1,  const bf16_t* __restrict__ wt,
               const float* __restrict__ c0all, const float* __restrict__ ball,
               const bf16_t* __restrict__ w3t, const float* __restrict__ b3,
               const bf16_t* __restrict__ w4t, const float* __restrict__ b4,
               bf16_t* h0, bf16_t* h1, bf16_t* g,
               float* __restrict__ out, float* __restrict__ hid_out,
               unsigned* __restrict__ bar)
{
    __shared__ float Ul[80 * UPITCH];   // 62720 B
    const int bx = blockIdx.x;

    // phase 0: h0 = xb @ w1t + b1   (208 tiles, grid-stride)
    for (int t = bx; t < 16 * 13; t += NBLK)
        gemm_tile<false, false>(xb, w1t, b1, h0, M_ROWS, HD, 256, (t & 15) << 6, t >> 4);
    grid_barrier(bar + 0, NBLK);

    // phases 1..12: SRU layers, ping-pong h0 <-> h1
    const int n0 = (bx & 15) << 6, bi = bx >> 4;
    bf16_t* hi = h0; bf16_t* ho = h1;
    for (int l = 0; l < NL; l++) {
        sru_tile(hi, ho, wt + (size_t)l * 3 * HD * HD,
                 c0all + (size_t)l * NB * HD, ball + (size_t)l * 2 * HD,
                 hid_out + (size_t)l * NB * HD, n0, bi, Ul);
        grid_barrier(bar + 1 + l, NBLK);
        bf16_t* tmp = hi; hi = ho; ho = tmp;
    }
    // 12 layers: final h landed in h0

    // phase 13: g = relu(h0 @ w3t + b3)
    for (int t = bx; t < 16 * 13; t += NBLK)
        gemm_tile<false, true>(h0, w3t, b3, g, M_ROWS, HD, HD, (t & 15) << 6, t >> 4);
    grid_barrier(bar + 13, NBLK);

    // phase 14: out = g @ w4t + b4   (18 x 13 tiles; overwrites h0 region)
    for (int t = bx; t < 18 * 13; t += NBLK)
        gemm_tile<true, false>(g, w4t, b4, out, M_ROWS, NOUT, HD, (t % 18) << 6, t / 18);
}

// ---------------------------------------------------------------------------
extern "C" void kernel_launch(void* const* d_in, const int* in_sizes, int n_in,
                              void* d_out, int out_size, void* d_ws, size_t ws_size,
                              hipStream_t stream)
{
    const float* x      = (const float*)d_in[0];
    const float* hidden = (const float*)d_in[1];
    const float* W1     = (const float*)d_in[2];
    const float* b1     = (const float*)d_in[3];
    const float* sruW   = (const float*)d_in[4];
    const float* srub   = (const float*)d_in[5];
    const float* W3     = (const float*)d_in[6];
    const float* b3     = (const float*)d_in[7];
    const float* W4     = (const float*)d_in[8];
    const float* b4     = (const float*)d_in[9];

    float* out     = (float*)d_out;
    float* hid_out = out + (size_t)M_ROWS * NOUT;   // [12,40,1024] fp32

    // h0 (bf16, 1.64 MB) aliases d_out's out0 region (3.50 MB fp32): dead by
    // phase 14, which reads only g and fully overwrites it.
    bf16_t* h0 = (bf16_t*)d_out;

    char* ws = (char*)d_ws;
    const size_t SZ_WT  = (size_t)NL * 3 * HD * HD * 2;    // 75,497,472
    const size_t SZ_W1  = (size_t)HD * 256 * 2;
    const size_t SZ_W3  = (size_t)HD * HD * 2;
    const size_t SZ_W4  = (size_t)1152 * HD * 2;
    const size_t SZ_XB  = (size_t)M_ROWS * 256 * 2;
    const size_t SZ_H   = (size_t)M_ROWS * HD * 2;

    bf16_t* wt  = (bf16_t*)ws;
    bf16_t* w1t = (bf16_t*)(ws + SZ_WT);
    bf16_t* w3t = (bf16_t*)(ws + SZ_WT + SZ_W1);
    bf16_t* w4t = (bf16_t*)(ws + SZ_WT + SZ_W1 + SZ_W3);
    bf16_t* xb  = (bf16_t*)(ws + SZ_WT + SZ_W1 + SZ_W3 + SZ_W4);
    bf16_t* h1  = (bf16_t*)(ws + SZ_WT + SZ_W1 + SZ_W3 + SZ_W4 + SZ_XB);
    bf16_t* g   = (bf16_t*)(ws + SZ_WT + SZ_W1 + SZ_W3 + SZ_W4 + SZ_XB + SZ_H);
    unsigned* bar = (unsigned*)(ws + SZ_WT + SZ_W1 + SZ_W3 + SZ_W4 + SZ_XB + 2 * SZ_H);

    const dim3 blk(256);

    hipMemsetAsync(bar, 0, 16 * sizeof(unsigned), stream);

    // prep: convert + transpose all weights to bf16 [n][k]
    convert_pad_x<<<M_ROWS, blk, 0, stream>>>(x, xb);
    transpose_convert<<<dim3(16, 4, 1),   blk, 0, stream>>>(W1,   w1t, FEA, HD,    256, HD);
    transpose_convert<<<dim3(48, 16, NL), blk, 0, stream>>>(sruW, wt,  HD,  3*HD, HD,  3*HD);
    transpose_convert<<<dim3(16, 16, 1),  blk, 0, stream>>>(W3,   w3t, HD,  HD,   HD,  HD);
    transpose_convert<<<dim3(18, 16, 1),  blk, 0, stream>>>(W4,   w4t, HD,  NOUT, HD,  1152);

    // fused network
    fused_net<<<dim3(NBLK), blk, 0, stream>>>(
        xb, w1t, b1, wt, hidden, srub, w3t, b3, w4t, b4,
        h0, h1, g, out, hid_out, bar);
}